// Round 3
// baseline (92.536 us; speedup 1.0000x reference)
//
#include <hip/hip_runtime.h>

#define TT 4096
#define BB 8
#define NB 64          // blocks per batch (stage A)
#define THREADS 256
#define MIN_GAP_C 5
#define MIN_SIZE_C 5

// Monotone float -> uint key: a > b (as floats) <=> fkey(a) > fkey(b) (as uints)
__device__ __forceinline__ unsigned int fkey(float f) {
    unsigned int b = __float_as_uint(f);
    return (b & 0x80000000u) ? ~b : (b | 0x80000000u);
}

__global__ __launch_bounds__(THREADS) void shl_stageA(const float* __restrict__ x,
                                                      unsigned long long* __restrict__ ws) {
    const int blk   = blockIdx.x;
    const int b     = blk / NB;
    const int chunk = blk - b * NB;
    const float* xb = x + b * TT;

    __shared__ float xs[TT];
    for (int k = threadIdx.x; k < TT; k += THREADS)
        xs[k] = xb[k];
    __syncthreads();

    unsigned long long best = 0ull;  // sentinel: below any real packed candidate
    // rows i = chunk + k*NB (interleaved for load balance)
    #pragma unroll 1
    for (int k = 0; k < TT / NB; ++k) {
        const int i = chunk + k * NB;
        if (i < MIN_GAP_C) continue;
        const int j0 = i + MIN_SIZE_C;
        if (j0 >= TT) continue;
        const float xi = xs[i];
        const unsigned int base = (unsigned int)i * (unsigned int)TT;
        for (int j = j0 + (int)threadIdx.x; j < TT; j += THREADS) {
            const float s = xi + xs[j];
            // larger value wins; tie -> smaller flat idx wins
            const unsigned long long p =
                ((unsigned long long)fkey(s) << 32)
              | (unsigned long long)(0xFFFFFFFFu - (base + (unsigned int)j));
            best = (p > best) ? p : best;
        }
    }

    // wave (64-lane) reduction
    #pragma unroll
    for (int off = 32; off > 0; off >>= 1) {
        const unsigned long long o = __shfl_down(best, off, 64);
        best = (o > best) ? o : best;
    }
    __shared__ unsigned long long wbest[THREADS / 64];
    const int wave = threadIdx.x >> 6;
    const int lane = threadIdx.x & 63;
    if (lane == 0) wbest[wave] = best;
    __syncthreads();
    if (threadIdx.x == 0) {
        unsigned long long r = wbest[0];
        #pragma unroll
        for (int w = 1; w < THREADS / 64; ++w) r = (wbest[w] > r) ? wbest[w] : r;
        ws[b * NB + chunk] = r;
    }
}

__global__ __launch_bounds__(64) void shl_stageB(const float* __restrict__ x,
                                                 const unsigned long long* __restrict__ ws,
                                                 float* __restrict__ out) {
    const int b = blockIdx.x;
    unsigned long long best = ws[b * NB + threadIdx.x];
    #pragma unroll
    for (int off = 32; off > 0; off >>= 1) {
        const unsigned long long o = __shfl_down(best, off, 64);
        best = (o > best) ? o : best;
    }
    if (threadIdx.x == 0) {
        const unsigned int flat = 0xFFFFFFFFu - (unsigned int)(best & 0xFFFFFFFFull);
        const int i = (int)(flat >> 12);    // / 4096
        const int j = (int)(flat & 4095u);  // % 4096
        const float* xb = x + b * TT;
        const float mval = xb[i] + xb[j];                      // bit-identical fp32 sum
        const float init_val = xb[1] + xb[1 + MIN_SIZE_C];
        const bool better = mval > init_val;
        out[b]          = better ? mval : init_val;
        out[BB + b]     = better ? (float)i : 1.0f;
        out[2 * BB + b] = better ? (float)j : (float)(1 + MIN_SIZE_C);
    }
}

extern "C" void kernel_launch(void* const* d_in, const int* in_sizes, int n_in,
                              void* d_out, int out_size, void* d_ws, size_t ws_size,
                              hipStream_t stream) {
    const float* x = (const float*)d_in[0];
    float* out = (float*)d_out;
    unsigned long long* ws = (unsigned long long*)d_ws;

    shl_stageA<<<dim3(BB * NB), dim3(THREADS), 0, stream>>>(x, ws);
    shl_stageB<<<dim3(BB), dim3(64), 0, stream>>>(x, ws, out);
}

// Round 4
// 69.226 us; speedup vs baseline: 1.3367x; 1.3367x over previous
//
#include <hip/hip_runtime.h>

#define TT 4096
#define GROUPS (TT / 4)   // 1024 float4 groups
#define BB 8
#define NB 256            // blocks per batch (stage A)
#define THREADS 256
#define ROWS (TT / NB)    // 16 rows per block
#define MIN_GAP_C 5
#define MIN_SIZE_C 5

// Monotone float -> uint key: a > b (as floats) <=> fkey(a) > fkey(b) (as uints)
__device__ __forceinline__ unsigned int fkey(float f) {
    unsigned int b = __float_as_uint(f);
    return (b & 0x80000000u) ? ~b : (b | 0x80000000u);
}

__global__ __launch_bounds__(THREADS) void shl_stageA(const float* __restrict__ x,
                                                      unsigned long long* __restrict__ ws) {
    const int blk   = blockIdx.x;
    const int b     = blk >> 8;     // / NB
    const int chunk = blk & 255;    // % NB
    const float* xb = x + b * TT;

    __shared__ float4 xs4[GROUPS];
    const float* xsf = (const float*)xs4;

    {
        const float4* xg = (const float4*)xb;
        for (int t = threadIdx.x; t < GROUPS; t += THREADS)
            xs4[t] = xg[t];
    }
    __syncthreads();

    // Cheap inner loop: float max + (row, group) tracking only.
    // Thread visits flat indices in ascending order, so strict '>' keeps
    // the first occurrence (matching jnp.argmax tie-break within a thread).
    float best = -INFINITY;
    int bi = 0, bg = 0;

    #pragma unroll 1
    for (int k = 0; k < ROWS; ++k) {
        const int i = chunk + (k << 8);
        if (i < MIN_GAP_C) continue;
        const int j0 = i + MIN_SIZE_C;
        if (j0 >= TT) break;                 // rows only get larger
        const int g0 = j0 >> 2;
        const float xi = xsf[i];             // uniform per block -> LDS broadcast
        for (int g = g0 + (int)threadIdx.x; g < GROUPS; g += THREADS) {
            const float4 v = xs4[g];
            float s0 = xi + v.x;
            float s1 = xi + v.y;
            float s2 = xi + v.z;
            float s3 = xi + v.w;
            if (g == g0) {                   // partial first group: mask j < j0
                const int jb = g << 2;
                if (jb     < j0) s0 = -INFINITY;
                if (jb + 1 < j0) s1 = -INFINITY;
                if (jb + 2 < j0) s2 = -INFINITY;
                if (jb + 3 < j0) s3 = -INFINITY;
            }
            const float m4 = fmaxf(fmaxf(s0, s1), fmaxf(s2, s3));
            if (m4 > best) { best = m4; bi = i; bg = g; }
        }
    }

    // Once-per-thread fixup: recover exact element within the winning group,
    // honoring validity (j >= j0) and first-occurrence (smallest k).
    unsigned long long packed = 0ull;        // sentinel below all real keys
    if (best > -INFINITY) {
        const float4 v = xs4[bg];
        const float xi = xsf[bi];
        const int jb = bg << 2;
        const int j0 = bi + MIN_SIZE_C;
        const float ss0 = xi + v.x;
        const float ss1 = xi + v.y;
        const float ss2 = xi + v.z;
        const float ss3 = xi + v.w;
        int ksel = 3;
        if (jb + 3 >= j0 && ss3 == best) ksel = 3;
        if (jb + 2 >= j0 && ss2 == best) ksel = 2;
        if (jb + 1 >= j0 && ss1 == best) ksel = 1;
        if (jb     >= j0 && ss0 == best) ksel = 0;
        const unsigned int flat = (unsigned int)bi * (unsigned int)TT
                                + (unsigned int)(jb + ksel);
        packed = ((unsigned long long)fkey(best) << 32)
               | (unsigned long long)(0xFFFFFFFFu - flat);
    }

    // wave (64-lane) reduction on packed key: value desc, then smallest flat idx
    #pragma unroll
    for (int off = 32; off > 0; off >>= 1) {
        const unsigned long long o = __shfl_down(packed, off, 64);
        packed = (o > packed) ? o : packed;
    }
    __shared__ unsigned long long wbest[THREADS / 64];
    const int wave = threadIdx.x >> 6;
    const int lane = threadIdx.x & 63;
    if (lane == 0) wbest[wave] = packed;
    __syncthreads();
    if (threadIdx.x == 0) {
        unsigned long long r = wbest[0];
        #pragma unroll
        for (int w = 1; w < THREADS / 64; ++w) r = (wbest[w] > r) ? wbest[w] : r;
        ws[b * NB + chunk] = r;
    }
}

__global__ __launch_bounds__(NB) void shl_stageB(const float* __restrict__ x,
                                                 const unsigned long long* __restrict__ ws,
                                                 float* __restrict__ out) {
    const int b = blockIdx.x;
    unsigned long long best = ws[b * NB + threadIdx.x];
    #pragma unroll
    for (int off = 32; off > 0; off >>= 1) {
        const unsigned long long o = __shfl_down(best, off, 64);
        best = (o > best) ? o : best;
    }
    __shared__ unsigned long long wbest[NB / 64];
    const int wave = threadIdx.x >> 6;
    const int lane = threadIdx.x & 63;
    if (lane == 0) wbest[wave] = best;
    __syncthreads();
    if (threadIdx.x == 0) {
        unsigned long long r = wbest[0];
        #pragma unroll
        for (int w = 1; w < NB / 64; ++w) r = (wbest[w] > r) ? wbest[w] : r;
        const unsigned int flat = 0xFFFFFFFFu - (unsigned int)(r & 0xFFFFFFFFull);
        const int i = (int)(flat >> 12);    // / 4096
        const int j = (int)(flat & 4095u);  // % 4096
        const float* xb = x + b * TT;
        const float mval = xb[i] + xb[j];   // bit-identical fp32 sum
        const float init_val = xb[1] + xb[1 + MIN_SIZE_C];
        const bool better = mval > init_val;
        out[b]          = better ? mval : init_val;
        out[BB + b]     = better ? (float)i : 1.0f;
        out[2 * BB + b] = better ? (float)j : (float)(1 + MIN_SIZE_C);
    }
}

extern "C" void kernel_launch(void* const* d_in, const int* in_sizes, int n_in,
                              void* d_out, int out_size, void* d_ws, size_t ws_size,
                              hipStream_t stream) {
    const float* x = (const float*)d_in[0];
    float* out = (float*)d_out;
    unsigned long long* ws = (unsigned long long*)d_ws;

    shl_stageA<<<dim3(BB * NB), dim3(THREADS), 0, stream>>>(x, ws);
    shl_stageB<<<dim3(BB), dim3(NB), 0, stream>>>(x, ws, out);
}

// Round 5
// 57.325 us; speedup vs baseline: 1.6142x; 1.2076x over previous
//
#include <hip/hip_runtime.h>

#define TT 4096
#define BB 8
#define THREADS 256
#define CH (TT / THREADS)   // 16 elements per thread
#define MIN_GAP_C 5
#define MIN_SIZE_C 5

// Monotone float -> uint key: a > b (floats) <=> fkey(a) > fkey(b) (uints)
__device__ __forceinline__ unsigned int fkey(float f) {
    unsigned int b = __float_as_uint(f);
    return (b & 0x80000000u) ? ~b : (b | 0x80000000u);
}

// Exact O(T) solution per batch row, one block per batch.
// Key fact: fp32 RN addition is monotone, so
//   max_j fl(x[i]+x[j]) over j>=i+5  ==  fl(x[i] + suffmax(i+5))
// where suffmax is the exact comparison-based suffix max (no rounding).
// First-occurrence argmax is recovered exactly:
//   i* = smallest i whose row value == M   (packed-key reduction)
//   j* = smallest j>=i*+5 with fl(x[i*]+x[j]) == M   (O(T) rescan)
__global__ __launch_bounds__(THREADS) void shl_fused(const float* __restrict__ x,
                                                     float* __restrict__ out) {
    const int b = blockIdx.x;
    const int t = threadIdx.x;
    const float* xb = x + b * TT;

    __shared__ float xs[TT];
    __shared__ float smax[TT];
    __shared__ float cbuf[THREADS];
    __shared__ unsigned long long wred[THREADS / 64];
    __shared__ unsigned int jred[THREADS / 64];
    __shared__ float sM;
    __shared__ int sI;

    // load x into LDS (vectorized)
    {
        const float4* xg = (const float4*)xb;
        float4* xs4 = (float4*)xs;
        for (int k = t; k < TT / 4; k += THREADS) xs4[k] = xg[k];
    }
    __syncthreads();

    // per-chunk max (chunk = 16 contiguous elements per thread)
    float cm = -INFINITY;
    #pragma unroll
    for (int e = 0; e < CH; ++e) cm = fmaxf(cm, xs[t * CH + e]);
    cbuf[t] = cm;
    __syncthreads();

    // inclusive suffix max over chunk maxes (Hillis-Steele, 8 steps)
    for (int off = 1; off < THREADS; off <<= 1) {
        const float v = cbuf[t];
        const float o = (t + off < THREADS) ? cbuf[t + off] : -INFINITY;
        __syncthreads();
        cbuf[t] = fmaxf(v, o);
        __syncthreads();
    }

    // per-element suffix max within each chunk (right-to-left)
    {
        float running = (t + 1 < THREADS) ? cbuf[t + 1] : -INFINITY;
        #pragma unroll
        for (int e = CH - 1; e >= 0; --e) {
            running = fmaxf(running, xs[t * CH + e]);
            smax[t * CH + e] = running;
        }
    }
    __syncthreads();

    // row values r_i = fl(x[i] + suffmax[i+5]); reduce (value desc, i asc)
    unsigned long long best = 0ull;   // sentinel below all real keys (x finite)
    #pragma unroll
    for (int e = 0; e < CH; ++e) {
        const int i = t * CH + e;
        if (i >= MIN_GAP_C && i + MIN_SIZE_C < TT) {
            const float r = xs[i] + smax[i + MIN_SIZE_C];
            const unsigned long long p = ((unsigned long long)fkey(r) << 32)
                | (unsigned long long)(0xFFFFFFFFu - (unsigned int)i);
            best = (p > best) ? p : best;
        }
    }
    const int wave = t >> 6, lane = t & 63;
    #pragma unroll
    for (int off = 32; off > 0; off >>= 1) {
        const unsigned long long o = __shfl_down(best, off, 64);
        best = (o > best) ? o : best;
    }
    if (lane == 0) wred[wave] = best;
    __syncthreads();
    if (t == 0) {
        unsigned long long r = wred[0];
        #pragma unroll
        for (int w = 1; w < THREADS / 64; ++w) r = (wred[w] > r) ? wred[w] : r;
        const int istar = (int)(0xFFFFFFFFu - (unsigned int)(r & 0xFFFFFFFFull));
        sI = istar;
        sM = xs[istar] + smax[istar + MIN_SIZE_C];  // bit-identical recompute of M
    }
    __syncthreads();
    const float M = sM;
    const int istar = sI;

    // rescan winning row: smallest j >= i*+5 with fl(x[i*]+x[j]) == M
    const float xi = xs[istar];
    const int j0 = istar + MIN_SIZE_C;
    unsigned int minj = 0xFFFFFFFFu;
    #pragma unroll
    for (int e = 0; e < CH; ++e) {
        const int j = t + e * THREADS;
        if (j >= j0 && (xi + xs[j]) == M)
            minj = ((unsigned int)j < minj) ? (unsigned int)j : minj;
    }
    #pragma unroll
    for (int off = 32; off > 0; off >>= 1) {
        const unsigned int o = __shfl_down(minj, off, 64);
        minj = (o < minj) ? o : minj;
    }
    if (lane == 0) jred[wave] = minj;
    __syncthreads();
    if (t == 0) {
        unsigned int jstar = jred[0];
        #pragma unroll
        for (int w = 1; w < THREADS / 64; ++w) jstar = (jred[w] < jstar) ? jred[w] : jstar;
        const float init_val = xs[1] + xs[1 + MIN_SIZE_C];
        const bool better = M > init_val;   // init pair (1,6) is outside valid set; strict >
        out[b]          = better ? M : init_val;
        out[BB + b]     = better ? (float)istar : 1.0f;
        out[2 * BB + b] = better ? (float)jstar : (float)(1 + MIN_SIZE_C);
    }
}

extern "C" void kernel_launch(void* const* d_in, const int* in_sizes, int n_in,
                              void* d_out, int out_size, void* d_ws, size_t ws_size,
                              hipStream_t stream) {
    const float* x = (const float*)d_in[0];
    float* out = (float*)d_out;
    (void)d_ws; (void)ws_size;

    shl_fused<<<dim3(BB), dim3(THREADS), 0, stream>>>(x, out);
}